// Round 23
// baseline (38.859 us; speedup 1.0000x reference)
//
#include <hip/hip_runtime.h>

#define NEG_SLOPE 0.2f
#define EPS 1e-6f

// x: [B=4, C=64, V=3, N=32768] f32, W: [64,64] f32, out like x
// d[o,v,n] = sum_i W[o,i]*x[i,v,n]; out = dot>=0 ? x : x - 0.8*(dot/(dnsq+eps))*d
// R22 (37.7us) with TPB=8: 512 blocks -> ALL co-resident (2/CU), no dispatch
// tail round, half the pipeline prologue ramps. Consecutive tiles per block
// (unlike R16's stride-768). Soft barrier (lgkmcnt-only) retained.

#define C_CH 64
#define V_DIM 3
#define N_FULL 32768
#define NT 32
#define THREADS 256
#define TPB 8

typedef __attribute__((ext_vector_type(8))) short bf16x8;
typedef __attribute__((ext_vector_type(4))) float f32x4;

__device__ __forceinline__ ushort f2bf(float f) {
    union { float f; unsigned u; } v; v.f = f;
    unsigned r = v.u + 0x7FFFu + ((v.u >> 16) & 1u);  // RNE
    return (ushort)(r >> 16);
}
__device__ __forceinline__ float bf2f(ushort s) {
    union { unsigned u; float f; } v; v.u = ((unsigned)s) << 16; return v.f;
}
// pack f32 -> (hi bf16 | lo bf16) in 4 VALU: round-half-up hi, truncated lo
__device__ __forceinline__ unsigned pack_hl(float x) {
    union { float f; unsigned u; } a; a.f = x;
    unsigned t0 = a.u + 0x8000u;
    union { unsigned u; float f; } hb; hb.u = t0 & 0xffff0000u;
    union { float f; unsigned u; } rb; rb.f = x - hb.f;
    return __builtin_amdgcn_perm(t0, rb.u, 0x07060302u);  // [t0.b3,t0.b2,rb.b3,rb.b2]
}

// dword-col swizzle for NT=32: XOR col bit 4 with row bit 3 -> <=2-way everywhere
__device__ __forceinline__ int swz(int row) { return ((row >> 3) & 1) << 4; }

// barrier that does NOT drain vmcnt: LDS visibility only.
__device__ __forceinline__ void soft_barrier() {
    asm volatile("s_waitcnt lgkmcnt(0)" ::: "memory");
    __builtin_amdgcn_s_barrier();
    __builtin_amdgcn_sched_barrier(0);
}

__global__ __launch_bounds__(THREADS, 3)
void vn_pipe(const float* __restrict__ x,
             const float* __restrict__ Wf,
             float* __restrict__ out) {
    // double buffer: LDS row = v*64 + i, packed (hi<<16)|lo. 2 x 24 KB.
    __shared__ unsigned xs[2][V_DIM * C_CH][NT];

    const int t     = threadIdx.x;
    const int tile0 = blockIdx.x * TPB;          // 4096 tiles total, 512 blocks
    const int b     = tile0 >> 10;               // batch (1024 % 8 == 0: no straddle)
    const float* xbase = x   + (size_t)b * (C_CH * V_DIM * N_FULL);
    float*       obase = out + (size_t)b * (C_CH * V_DIM * N_FULL);

    const int lane = t & 63;
    const int w    = t >> 6;   // 0..3
    const int wo   = w >> 1;   // o-half -> 32 channels (via m loop)
    const int wn   = w & 1;    // n-half -> 16 cols
    const int l4   = lane & 15;
    const int hi   = lane >> 4;

    // ---- prologue: issue tile0 loads (6 float4/thread)
    float4 xr[6];
    {
        const float* xb = xbase + ((tile0 & 1023) << 5);
        #pragma unroll
        for (int it = 0; it < 6; ++it) {
            int idx = t + it * THREADS;
            xr[it] = *(const float4*)(xb + (size_t)(idx >> 3) * N_FULL + ((idx & 7) << 2));
        }
    }

    // ---- A fragments (W) under the load shadow: row o = wo*32+m*16+l4,
    // k = kh*32+hi*8+j; RNE hi/lo split
    bf16x8 Ah[2][2], Al[2][2];
    #pragma unroll
    for (int m = 0; m < 2; ++m)
        #pragma unroll
        for (int kh = 0; kh < 2; ++kh) {
            const float* wp = Wf + (size_t)(wo * 32 + m * 16 + l4) * C_CH + kh * 32 + hi * 8;
            float4 wa = *(const float4*)wp;
            float4 wb = *(const float4*)(wp + 4);
            float wf[8] = {wa.x, wa.y, wa.z, wa.w, wb.x, wb.y, wb.z, wb.w};
            bf16x8 h, l;
            #pragma unroll
            for (int j = 0; j < 8; ++j) {
                ushort hb = f2bf(wf[j]);
                h[j] = (short)hb;
                l[j] = (short)f2bf(wf[j] - bf2f(hb));
            }
            Ah[m][kh] = h; Al[m][kh] = l;
        }

    // ---- identity A-fragments: Aid_m[row][k] = (k == m*16+row) ? 1 : 0
    bf16x8 Aid0, Aid1;
    {
        const int j1 = l4 & 7;
        const bool h0 = (hi == (l4 >> 3));
        const bool h1 = (hi == 2 + (l4 >> 3));
        #pragma unroll
        for (int j = 0; j < 8; ++j) {
            Aid0[j] = (short)((h0 && j == j1) ? 0x3F80 : 0);
            Aid1[j] = (short)((h1 && j == j1) ? 0x3F80 : 0);
        }
    }

    // ---- pack tile0 -> buf0
    #pragma unroll
    for (int it = 0; it < 6; ++it) {
        int idx = t + it * THREADS;
        int r   = idx >> 3;
        int c4  = (idx & 7) << 2;
        int i   = (r * 171) >> 9;        // r/3 (exact for r<768)
        int v   = r - 3 * i;
        int rowp = v * 64 + i;
        unsigned p[4] = {pack_hl(xr[it].x), pack_hl(xr[it].y),
                         pack_hl(xr[it].z), pack_hl(xr[it].w)};
        *(uint4*)&xs[0][rowp][c4 ^ swz(rowp)] = *(const uint4*)p;
    }
    soft_barrier();

    const int acol = (wn * 16 + l4) ^ ((hi & 1) << 4);  // B-frag col, const
    const int n    = wn * 16 + l4;

    #pragma unroll
    for (int tt = 0; tt < TPB; ++tt) {
        const int cur = tt & 1;
        const int n0c = ((tile0 + tt) & 1023) << 5;

        // ---- issue NEXT tile's loads first (fly under compute below)
        if (tt + 1 < TPB) {
            const float* xb = xbase + (((tile0 + tt + 1) & 1023) << 5);
            #pragma unroll
            for (int it = 0; it < 6; ++it) {
                int idx = t + it * THREADS;
                xr[it] = *(const float4*)(xb + (size_t)(idx >> 3) * N_FULL + ((idx & 7) << 2));
            }
        }

        // ---- compute tile tt from xs[cur]; accx = exact x via identity MFMA
        f32x4 acc[2][3], accx[2][3];
        #pragma unroll
        for (int m = 0; m < 2; ++m)
            #pragma unroll
            for (int v = 0; v < 3; ++v) {
                acc[m][v]  = (f32x4){0.f, 0.f, 0.f, 0.f};
                accx[m][v] = (f32x4){0.f, 0.f, 0.f, 0.f};
            }

        #pragma unroll
        for (int v = 0; v < 3; ++v) {
            #pragma unroll
            for (int kh = 0; kh < 2; ++kh) {
                const int rowb = v * 64 + kh * 32 + hi * 8;
                unsigned p[8];
                #pragma unroll
                for (int j = 0; j < 8; ++j)
                    p[j] = xs[cur][rowb + j][acol];
                union { bf16x8 v8; unsigned d[4]; } BH, BL;
                #pragma unroll
                for (int q = 0; q < 4; ++q) {
                    BH.d[q] = __builtin_amdgcn_perm(p[2 * q + 1], p[2 * q], 0x07060302u);
                    BL.d[q] = __builtin_amdgcn_perm(p[2 * q + 1], p[2 * q], 0x05040100u);
                }
                #pragma unroll
                for (int m = 0; m < 2; ++m) {
                    acc[m][v] = __builtin_amdgcn_mfma_f32_16x16x32_bf16(Ah[m][kh], BH.v8, acc[m][v], 0, 0, 0);
                    acc[m][v] = __builtin_amdgcn_mfma_f32_16x16x32_bf16(Ah[m][kh], BL.v8, acc[m][v], 0, 0, 0);
                    acc[m][v] = __builtin_amdgcn_mfma_f32_16x16x32_bf16(Al[m][kh], BH.v8, acc[m][v], 0, 0, 0);
                }
                if (kh == wo) {  // wave-uniform: identity block lives at kh==wo
                    accx[0][v] = __builtin_amdgcn_mfma_f32_16x16x32_bf16(Aid0, BH.v8, accx[0][v], 0, 0, 0);
                    accx[0][v] = __builtin_amdgcn_mfma_f32_16x16x32_bf16(Aid0, BL.v8, accx[0][v], 0, 0, 0);
                    accx[1][v] = __builtin_amdgcn_mfma_f32_16x16x32_bf16(Aid1, BH.v8, accx[1][v], 0, 0, 0);
                    accx[1][v] = __builtin_amdgcn_mfma_f32_16x16x32_bf16(Aid1, BL.v8, accx[1][v], 0, 0, 0);
                }
            }
        }

        // ---- epilogue for tile tt: C/D col=l4 (n), row=hi*4+rr; x from accx
        float* ob = obase + n0c + n;
        #pragma unroll
        for (int m = 0; m < 2; ++m) {
            #pragma unroll
            for (int rr = 0; rr < 4; ++rr) {
                const int o = wo * 32 + m * 16 + hi * 4 + rr;
                float xv[3], dv[3];
                #pragma unroll
                for (int v = 0; v < 3; ++v) {
                    xv[v] = accx[m][v][rr];
                    dv[v] = acc[m][v][rr];
                }
                float dot  = xv[0] * dv[0] + xv[1] * dv[1] + xv[2] * dv[2];
                float dnsq = dv[0] * dv[0] + dv[1] * dv[1] + dv[2] * dv[2];
                float f = (1.0f - NEG_SLOPE) * dot * __builtin_amdgcn_rcpf(dnsq + EPS);
                f = (dot >= 0.f) ? 0.f : f;
                float o0 = fmaf(-f, dv[0], xv[0]);
                float o1 = fmaf(-f, dv[1], xv[1]);
                float o2 = fmaf(-f, dv[2], xv[2]);
                float* op = ob + (size_t)o * (V_DIM * N_FULL);
                op[0 * N_FULL] = o0;
                op[1 * N_FULL] = o1;
                op[2 * N_FULL] = o2;
            }
        }

        // ---- pack NEXT tile into the other buffer, then soft fence
        if (tt + 1 < TPB) {
            #pragma unroll
            for (int it = 0; it < 6; ++it) {
                int idx = t + it * THREADS;
                int r   = idx >> 3;
                int c4  = (idx & 7) << 2;
                int i   = (r * 171) >> 9;
                int v   = r - 3 * i;
                int rowp = v * 64 + i;
                unsigned p[4] = {pack_hl(xr[it].x), pack_hl(xr[it].y),
                                 pack_hl(xr[it].z), pack_hl(xr[it].w)};
                *(uint4*)&xs[cur ^ 1][rowp][c4 ^ swz(rowp)] = *(const uint4*)p;
            }
            soft_barrier();
        }
    }
}

extern "C" void kernel_launch(void* const* d_in, const int* in_sizes, int n_in,
                              void* d_out, int out_size, void* d_ws, size_t ws_size,
                              hipStream_t stream) {
    const float* x = (const float*)d_in[0];
    const float* W = (const float*)d_in[1];
    float* out = (float*)d_out;

    const int B = 4;
    const int blocks = B * (N_FULL / NT) / TPB;  // 512
    vn_pipe<<<blocks, THREADS, 0, stream>>>(x, W, out);
}

// Round 24
// 37.664 us; speedup vs baseline: 1.0317x; 1.0317x over previous
//
#include <hip/hip_runtime.h>

#define NEG_SLOPE 0.2f
#define EPS 1e-6f

// x: [B=4, C=64, V=3, N=32768] f32, W: [64,64] f32, out like x
// d[o,v,n] = sum_i W[o,i]*x[i,v,n]; out = dot>=0 ? x : x - 0.8*(dot/(dnsq+eps))*d
// FINAL: bf16 MFMA (A=W frag, B=x frag), hi/lo 3-product split (fp32-grade,
// absmax 0.0156 << 0.108 threshold). Cross-tile double-buffered pipeline
// (TPB=4), accx identity-MFMA epilogue (zero epilogue LDS), soft barrier
// (lgkmcnt-only). 2048 tiles -> 1024 blocks x 256 thr, 48 KB LDS, 3 blk/CU.
// 37.7us steady-state; 147 MB HBM traffic @ ~3.9 TB/s effective.

#define C_CH 64
#define V_DIM 3
#define N_FULL 32768
#define NT 32
#define THREADS 256
#define TPB 4

typedef __attribute__((ext_vector_type(8))) short bf16x8;
typedef __attribute__((ext_vector_type(4))) float f32x4;

__device__ __forceinline__ ushort f2bf(float f) {
    union { float f; unsigned u; } v; v.f = f;
    unsigned r = v.u + 0x7FFFu + ((v.u >> 16) & 1u);  // RNE
    return (ushort)(r >> 16);
}
__device__ __forceinline__ float bf2f(ushort s) {
    union { unsigned u; float f; } v; v.u = ((unsigned)s) << 16; return v.f;
}
// pack f32 -> (hi bf16 | lo bf16) in 4 VALU: round-half-up hi, truncated lo
__device__ __forceinline__ unsigned pack_hl(float x) {
    union { float f; unsigned u; } a; a.f = x;
    unsigned t0 = a.u + 0x8000u;
    union { unsigned u; float f; } hb; hb.u = t0 & 0xffff0000u;
    union { float f; unsigned u; } rb; rb.f = x - hb.f;
    return __builtin_amdgcn_perm(t0, rb.u, 0x07060302u);  // [t0.b3,t0.b2,rb.b3,rb.b2]
}

// dword-col swizzle for NT=32: XOR col bit 4 with row bit 3 -> <=2-way everywhere
__device__ __forceinline__ int swz(int row) { return ((row >> 3) & 1) << 4; }

// barrier that does NOT drain vmcnt: LDS visibility only.
__device__ __forceinline__ void soft_barrier() {
    asm volatile("s_waitcnt lgkmcnt(0)" ::: "memory");
    __builtin_amdgcn_s_barrier();
    __builtin_amdgcn_sched_barrier(0);
}

__global__ __launch_bounds__(THREADS, 3)
void vn_pipe(const float* __restrict__ x,
             const float* __restrict__ Wf,
             float* __restrict__ out) {
    // double buffer: LDS row = v*64 + i, packed (hi<<16)|lo. 2 x 24 KB.
    __shared__ unsigned xs[2][V_DIM * C_CH][NT];

    const int t     = threadIdx.x;
    const int tile0 = blockIdx.x * TPB;          // 4096 tiles total, 1024 blocks
    const int b     = tile0 >> 10;               // batch (blocks never straddle)
    const float* xbase = x   + (size_t)b * (C_CH * V_DIM * N_FULL);
    float*       obase = out + (size_t)b * (C_CH * V_DIM * N_FULL);

    const int lane = t & 63;
    const int w    = t >> 6;   // 0..3
    const int wo   = w >> 1;   // o-half -> 32 channels (via m loop)
    const int wn   = w & 1;    // n-half -> 16 cols
    const int l4   = lane & 15;
    const int hi   = lane >> 4;

    // ---- prologue: issue tile0 loads (6 float4/thread)
    float4 xr[6];
    {
        const float* xb = xbase + ((tile0 & 1023) << 5);
        #pragma unroll
        for (int it = 0; it < 6; ++it) {
            int idx = t + it * THREADS;
            xr[it] = *(const float4*)(xb + (size_t)(idx >> 3) * N_FULL + ((idx & 7) << 2));
        }
    }

    // ---- A fragments (W) under the load shadow: row o = wo*32+m*16+l4,
    // k = kh*32+hi*8+j; RNE hi/lo split
    bf16x8 Ah[2][2], Al[2][2];
    #pragma unroll
    for (int m = 0; m < 2; ++m)
        #pragma unroll
        for (int kh = 0; kh < 2; ++kh) {
            const float* wp = Wf + (size_t)(wo * 32 + m * 16 + l4) * C_CH + kh * 32 + hi * 8;
            float4 wa = *(const float4*)wp;
            float4 wb = *(const float4*)(wp + 4);
            float wf[8] = {wa.x, wa.y, wa.z, wa.w, wb.x, wb.y, wb.z, wb.w};
            bf16x8 h, l;
            #pragma unroll
            for (int j = 0; j < 8; ++j) {
                ushort hb = f2bf(wf[j]);
                h[j] = (short)hb;
                l[j] = (short)f2bf(wf[j] - bf2f(hb));
            }
            Ah[m][kh] = h; Al[m][kh] = l;
        }

    // ---- identity A-fragments: Aid_m[row][k] = (k == m*16+row) ? 1 : 0
    bf16x8 Aid0, Aid1;
    {
        const int j1 = l4 & 7;
        const bool h0 = (hi == (l4 >> 3));
        const bool h1 = (hi == 2 + (l4 >> 3));
        #pragma unroll
        for (int j = 0; j < 8; ++j) {
            Aid0[j] = (short)((h0 && j == j1) ? 0x3F80 : 0);
            Aid1[j] = (short)((h1 && j == j1) ? 0x3F80 : 0);
        }
    }

    // ---- pack tile0 -> buf0
    #pragma unroll
    for (int it = 0; it < 6; ++it) {
        int idx = t + it * THREADS;
        int r   = idx >> 3;
        int c4  = (idx & 7) << 2;
        int i   = (r * 171) >> 9;        // r/3 (exact for r<768)
        int v   = r - 3 * i;
        int rowp = v * 64 + i;
        unsigned p[4] = {pack_hl(xr[it].x), pack_hl(xr[it].y),
                         pack_hl(xr[it].z), pack_hl(xr[it].w)};
        *(uint4*)&xs[0][rowp][c4 ^ swz(rowp)] = *(const uint4*)p;
    }
    soft_barrier();

    const int acol = (wn * 16 + l4) ^ ((hi & 1) << 4);  // B-frag col, const
    const int n    = wn * 16 + l4;

    #pragma unroll
    for (int tt = 0; tt < TPB; ++tt) {
        const int cur = tt & 1;
        const int n0c = ((tile0 + tt) & 1023) << 5;

        // ---- issue NEXT tile's loads first (fly under compute below)
        if (tt + 1 < TPB) {
            const float* xb = xbase + (((tile0 + tt + 1) & 1023) << 5);
            #pragma unroll
            for (int it = 0; it < 6; ++it) {
                int idx = t + it * THREADS;
                xr[it] = *(const float4*)(xb + (size_t)(idx >> 3) * N_FULL + ((idx & 7) << 2));
            }
        }

        // ---- compute tile tt from xs[cur]; accx = exact x via identity MFMA
        f32x4 acc[2][3], accx[2][3];
        #pragma unroll
        for (int m = 0; m < 2; ++m)
            #pragma unroll
            for (int v = 0; v < 3; ++v) {
                acc[m][v]  = (f32x4){0.f, 0.f, 0.f, 0.f};
                accx[m][v] = (f32x4){0.f, 0.f, 0.f, 0.f};
            }

        #pragma unroll
        for (int v = 0; v < 3; ++v) {
            #pragma unroll
            for (int kh = 0; kh < 2; ++kh) {
                const int rowb = v * 64 + kh * 32 + hi * 8;
                unsigned p[8];
                #pragma unroll
                for (int j = 0; j < 8; ++j)
                    p[j] = xs[cur][rowb + j][acol];
                union { bf16x8 v8; unsigned d[4]; } BH, BL;
                #pragma unroll
                for (int q = 0; q < 4; ++q) {
                    BH.d[q] = __builtin_amdgcn_perm(p[2 * q + 1], p[2 * q], 0x07060302u);
                    BL.d[q] = __builtin_amdgcn_perm(p[2 * q + 1], p[2 * q], 0x05040100u);
                }
                #pragma unroll
                for (int m = 0; m < 2; ++m) {
                    acc[m][v] = __builtin_amdgcn_mfma_f32_16x16x32_bf16(Ah[m][kh], BH.v8, acc[m][v], 0, 0, 0);
                    acc[m][v] = __builtin_amdgcn_mfma_f32_16x16x32_bf16(Ah[m][kh], BL.v8, acc[m][v], 0, 0, 0);
                    acc[m][v] = __builtin_amdgcn_mfma_f32_16x16x32_bf16(Al[m][kh], BH.v8, acc[m][v], 0, 0, 0);
                }
                if (kh == wo) {  // wave-uniform: identity block lives at kh==wo
                    accx[0][v] = __builtin_amdgcn_mfma_f32_16x16x32_bf16(Aid0, BH.v8, accx[0][v], 0, 0, 0);
                    accx[0][v] = __builtin_amdgcn_mfma_f32_16x16x32_bf16(Aid0, BL.v8, accx[0][v], 0, 0, 0);
                    accx[1][v] = __builtin_amdgcn_mfma_f32_16x16x32_bf16(Aid1, BH.v8, accx[1][v], 0, 0, 0);
                    accx[1][v] = __builtin_amdgcn_mfma_f32_16x16x32_bf16(Aid1, BL.v8, accx[1][v], 0, 0, 0);
                }
            }
        }

        // ---- epilogue for tile tt: C/D col=l4 (n), row=hi*4+rr; x from accx
        float* ob = obase + n0c + n;
        #pragma unroll
        for (int m = 0; m < 2; ++m) {
            #pragma unroll
            for (int rr = 0; rr < 4; ++rr) {
                const int o = wo * 32 + m * 16 + hi * 4 + rr;
                float xv[3], dv[3];
                #pragma unroll
                for (int v = 0; v < 3; ++v) {
                    xv[v] = accx[m][v][rr];
                    dv[v] = acc[m][v][rr];
                }
                float dot  = xv[0] * dv[0] + xv[1] * dv[1] + xv[2] * dv[2];
                float dnsq = dv[0] * dv[0] + dv[1] * dv[1] + dv[2] * dv[2];
                float f = (1.0f - NEG_SLOPE) * dot * __builtin_amdgcn_rcpf(dnsq + EPS);
                f = (dot >= 0.f) ? 0.f : f;
                float o0 = fmaf(-f, dv[0], xv[0]);
                float o1 = fmaf(-f, dv[1], xv[1]);
                float o2 = fmaf(-f, dv[2], xv[2]);
                float* op = ob + (size_t)o * (V_DIM * N_FULL);
                op[0 * N_FULL] = o0;
                op[1 * N_FULL] = o1;
                op[2 * N_FULL] = o2;
            }
        }

        // ---- pack NEXT tile into the other buffer, then soft fence
        if (tt + 1 < TPB) {
            #pragma unroll
            for (int it = 0; it < 6; ++it) {
                int idx = t + it * THREADS;
                int r   = idx >> 3;
                int c4  = (idx & 7) << 2;
                int i   = (r * 171) >> 9;
                int v   = r - 3 * i;
                int rowp = v * 64 + i;
                unsigned p[4] = {pack_hl(xr[it].x), pack_hl(xr[it].y),
                                 pack_hl(xr[it].z), pack_hl(xr[it].w)};
                *(uint4*)&xs[cur ^ 1][rowp][c4 ^ swz(rowp)] = *(const uint4*)p;
            }
            soft_barrier();
        }
    }
}

extern "C" void kernel_launch(void* const* d_in, const int* in_sizes, int n_in,
                              void* d_out, int out_size, void* d_ws, size_t ws_size,
                              hipStream_t stream) {
    const float* x = (const float*)d_in[0];
    const float* W = (const float*)d_in[1];
    float* out = (float*)d_out;

    const int B = 4;
    const int blocks = B * (N_FULL / NT) / TPB;  // 1024
    vn_pipe<<<blocks, THREADS, 0, stream>>>(x, W, out);
}